// Round 7
// baseline (333.557 us; speedup 1.0000x reference)
//
#include <hip/hip_runtime.h>

#define NN 100000
#define NE 1600000
#define SD 128
#define HD 32
#define NV4 25000      // NN/4 (exact)
#define NSB 98         // ceil(NV4/256)
#define NC 8           // histogram copies (XCD count)

// ---------- pass 1: in-degree count into XCD-private copy + per-edge rank ----------
__global__ __launch_bounds__(256) void k_count(const int* __restrict__ dst,
                                               unsigned* __restrict__ cnt,
                                               unsigned* __restrict__ rank) {
    int e = blockIdx.x * 256 + threadIdx.x;          // exact NE/256
    unsigned c = blockIdx.x & (NC - 1);              // copy == XCD under round-robin dispatch
    int d = dst[e];
    rank[e] = atomicAdd(&cnt[c * NN + d], 1u);
}

// ---------- scan: per-block sums (over all copies) ----------
__global__ __launch_bounds__(256) void k_scanA(const uint4* __restrict__ cnt4,
                                               unsigned* __restrict__ bsum) {
    __shared__ unsigned ts[256];
    int tid = threadIdx.x;
    int f = blockIdx.x * 256 + tid;
    unsigned s = 0;
    if (f < NV4) {
#pragma unroll
        for (int c = 0; c < NC; ++c) {
            uint4 v = cnt4[c * NV4 + f];
            s += v.x + v.y + v.z + v.w;
        }
    }
    ts[tid] = s; __syncthreads();
    for (int off = 128; off > 0; off >>= 1) {
        if (tid < off) ts[tid] += ts[tid + off];
        __syncthreads();
    }
    if (tid == 0) bsum[blockIdx.x] = ts[0];
}

__global__ __launch_bounds__(128) void k_scanB(unsigned* __restrict__ bsum,
                                               unsigned* __restrict__ rowptr) {
    __shared__ unsigned s[128];
    int tid = threadIdx.x;
    unsigned v = (tid < NSB) ? bsum[tid] : 0u;
    s[tid] = v; __syncthreads();
    for (int off = 1; off < 128; off <<= 1) {
        unsigned t = (tid >= off) ? s[tid - off] : 0u;
        __syncthreads();
        s[tid] += t;
        __syncthreads();
    }
    if (tid < NSB) bsum[tid] = s[tid] - v;   // exclusive block offsets
    if (tid == 0) rowptr[NN] = NE;
}

// ---------- scan finalize: rowptr + dinv + per-copy bases ----------
__global__ __launch_bounds__(256) void k_scanC(const uint4* __restrict__ cnt4,
                                               const unsigned* __restrict__ bsum,
                                               uint4* __restrict__ rowptr4,
                                               float4* __restrict__ dinv4,
                                               uint4* __restrict__ base4) {
    __shared__ unsigned ts[256];
    int tid = threadIdx.x;
    int f = blockIdx.x * 256 + tid;
    uint4 pc[NC];
    uint4 t = {0, 0, 0, 0};
    if (f < NV4) {
#pragma unroll
        for (int c = 0; c < NC; ++c) {
            pc[c] = cnt4[c * NV4 + f];
            t.x += pc[c].x; t.y += pc[c].y; t.z += pc[c].z; t.w += pc[c].w;
        }
    } else {
#pragma unroll
        for (int c = 0; c < NC; ++c) pc[c] = make_uint4(0, 0, 0, 0);
    }
    unsigned tsum = t.x + t.y + t.z + t.w;
    ts[tid] = tsum; __syncthreads();
    for (int off = 1; off < 256; off <<= 1) {
        unsigned v = (tid >= off) ? ts[tid - off] : 0u;
        __syncthreads();
        ts[tid] += v;
        __syncthreads();
    }
    unsigned ebase = ts[tid] - tsum + bsum[blockIdx.x];  // exclusive prefix
    if (f < NV4) {
        uint4 r;
        r.x = ebase;
        r.y = r.x + t.x;
        r.z = r.y + t.y;
        r.w = r.z + t.z;
        rowptr4[f] = r;
        float4 dv;
        dv.x = rsqrtf((float)t.x + 1.0f);
        dv.y = rsqrtf((float)t.y + 1.0f);
        dv.z = rsqrtf((float)t.z + 1.0f);
        dv.w = rsqrtf((float)t.w + 1.0f);
        dinv4[f] = dv;
        uint4 run = r;
#pragma unroll
        for (int c = 0; c < NC; ++c) {               // base[c][n] = rowptr[n]+prefix(cnt)
            base4[c * NV4 + f] = run;
            run.x += pc[c].x; run.y += pc[c].y; run.z += pc[c].z; run.w += pc[c].w;
        }
    }
}

// ---------- pass 2: CSR fill, no atomics, XCD-local base reads ----------
__global__ __launch_bounds__(256) void k_fill(const int* __restrict__ src,
                                              const int* __restrict__ dst,
                                              const unsigned* __restrict__ rank,
                                              const unsigned* __restrict__ base,
                                              unsigned* __restrict__ edat) {
    int e = blockIdx.x * 256 + threadIdx.x;          // exact NE/256, same grid as k_count
    unsigned c = blockIdx.x & (NC - 1);              // must match k_count's copy choice
    int d = dst[e];
    edat[base[c * NN + d] + rank[e]] = (unsigned)src[e];
}

// ---------- hw = (X @ W1) * dinv[n] : 256 nodes/block, thread = 8n x 4f ----------
__global__ __launch_bounds__(256) void k_mm128(const float* __restrict__ X,
                                               const float* __restrict__ W,
                                               const float* __restrict__ dinv,
                                               float* __restrict__ out) {
    __shared__ float Wls[SD * HD];       // 16 KB
    __shared__ float xT[32][260];        // 33.3 KB; rows 16B-aligned, reads 2-way (free)
    int tid = threadIdx.x;
    {   // stage W: 4096 floats, float4
        const float4* W4 = (const float4*)W;
        float4* Wl4 = (float4*)Wls;
        for (int i = tid; i < SD * HD / 4; i += 256) Wl4[i] = W4[i];
    }
    int nb = blockIdx.x * 256;
    int g = tid & 7;        // feature quad: j = 4g..4g+3
    int q = tid >> 3;       // node octet:   n = 8q..8q+7
    float acc[8][4] = {};
    for (int kc = 0; kc < SD; kc += 32) {
        __syncthreads();
        for (int i = tid; i < 256 * 8; i += 256) {
            int n = i >> 3, k4 = i & 7;
            int node = nb + n;
            float4 v = (node < NN) ? *(const float4*)&X[(size_t)node * SD + kc + k4 * 4]
                                   : make_float4(0.f, 0.f, 0.f, 0.f);
            xT[k4 * 4 + 0][n] = v.x;
            xT[k4 * 4 + 1][n] = v.y;
            xT[k4 * 4 + 2][n] = v.z;
            xT[k4 * 4 + 3][n] = v.w;
        }
        __syncthreads();
#pragma unroll
        for (int kk = 0; kk < 32; ++kk) {
            const float4 xa = *(const float4*)&xT[kk][q * 8];
            const float4 xb = *(const float4*)&xT[kk][q * 8 + 4];
            const float4 wv = *(const float4*)&Wls[(kc + kk) * HD + g * 4];
            acc[0][0] = fmaf(xa.x, wv.x, acc[0][0]);
            acc[0][1] = fmaf(xa.x, wv.y, acc[0][1]);
            acc[0][2] = fmaf(xa.x, wv.z, acc[0][2]);
            acc[0][3] = fmaf(xa.x, wv.w, acc[0][3]);
            acc[1][0] = fmaf(xa.y, wv.x, acc[1][0]);
            acc[1][1] = fmaf(xa.y, wv.y, acc[1][1]);
            acc[1][2] = fmaf(xa.y, wv.z, acc[1][2]);
            acc[1][3] = fmaf(xa.y, wv.w, acc[1][3]);
            acc[2][0] = fmaf(xa.z, wv.x, acc[2][0]);
            acc[2][1] = fmaf(xa.z, wv.y, acc[2][1]);
            acc[2][2] = fmaf(xa.z, wv.z, acc[2][2]);
            acc[2][3] = fmaf(xa.z, wv.w, acc[2][3]);
            acc[3][0] = fmaf(xa.w, wv.x, acc[3][0]);
            acc[3][1] = fmaf(xa.w, wv.y, acc[3][1]);
            acc[3][2] = fmaf(xa.w, wv.z, acc[3][2]);
            acc[3][3] = fmaf(xa.w, wv.w, acc[3][3]);
            acc[4][0] = fmaf(xb.x, wv.x, acc[4][0]);
            acc[4][1] = fmaf(xb.x, wv.y, acc[4][1]);
            acc[4][2] = fmaf(xb.x, wv.z, acc[4][2]);
            acc[4][3] = fmaf(xb.x, wv.w, acc[4][3]);
            acc[5][0] = fmaf(xb.y, wv.x, acc[5][0]);
            acc[5][1] = fmaf(xb.y, wv.y, acc[5][1]);
            acc[5][2] = fmaf(xb.y, wv.z, acc[5][2]);
            acc[5][3] = fmaf(xb.y, wv.w, acc[5][3]);
            acc[6][0] = fmaf(xb.z, wv.x, acc[6][0]);
            acc[6][1] = fmaf(xb.z, wv.y, acc[6][1]);
            acc[6][2] = fmaf(xb.z, wv.z, acc[6][2]);
            acc[6][3] = fmaf(xb.z, wv.w, acc[6][3]);
            acc[7][0] = fmaf(xb.w, wv.x, acc[7][0]);
            acc[7][1] = fmaf(xb.w, wv.y, acc[7][1]);
            acc[7][2] = fmaf(xb.w, wv.z, acc[7][2]);
            acc[7][3] = fmaf(xb.w, wv.w, acc[7][3]);
        }
    }
#pragma unroll
    for (int r = 0; r < 8; ++r) {
        int node = nb + q * 8 + r;
        if (node < NN) {
            float dv = dinv[node];
            float4 o = {acc[r][0] * dv, acc[r][1] * dv, acc[r][2] * dv, acc[r][3] * dv};
            *(float4*)&out[(size_t)node * HD + g * 4] = o;
        }
    }
}

// ---------- gather aggregation; 32 lanes = 32 features per node ----------
// v[j] = dinv[n]*(sum_in hw[s][j] + hw[n][j]) + bias[j]
// MODE 1: hw2[n][j'] = (sum_j v[j]*Wa[j][j']) * dinv[n]   (fused 32x32 matmul)
// MODE 2: heads: outw[n] = { dinv*sum relu(v)*Wa, dinv*sum v*Wb }
template <int MODE>
__global__ __launch_bounds__(256) void k_gather(const unsigned* __restrict__ edat,
                                                const unsigned* __restrict__ rowptr,
                                                const float* __restrict__ dinv,
                                                const float* __restrict__ hw,
                                                const float* __restrict__ bias,
                                                const float* __restrict__ Wa,
                                                const float* __restrict__ Wb,
                                                float* __restrict__ outw) {
    int gid = blockIdx.x * 256 + threadIdx.x;        // exact NN*32/256
    int n = gid >> 5, j = gid & 31;
    unsigned s0 = rowptr[n], s1 = rowptr[n + 1];
    float acc = 0.f;
    unsigned i = s0;
    for (; i + 4 <= s1; i += 4) {                    // 4-deep: 4 row-loads in flight
        unsigned e0 = edat[i], e1 = edat[i + 1], e2 = edat[i + 2], e3 = edat[i + 3];
        float v0 = hw[(size_t)e0 * HD + j];
        float v1 = hw[(size_t)e1 * HD + j];
        float v2 = hw[(size_t)e2 * HD + j];
        float v3 = hw[(size_t)e3 * HD + j];
        acc += (v0 + v1) + (v2 + v3);
    }
    for (; i < s1; ++i) acc += hw[(size_t)edat[i] * HD + j];
    float dv = dinv[n];
    float v = dv * (acc + hw[(size_t)n * HD + j]) + bias[j];
    if (MODE == 1) {
        float h2 = 0.f;
#pragma unroll
        for (int jj = 0; jj < 32; ++jj)
            h2 = fmaf(__shfl(v, jj, 32), Wa[jj * HD + j], h2);
        outw[(size_t)n * HD + j] = h2 * dv;
    } else {
        float a = fmaxf(v, 0.f) * Wa[j];
        float b = v * Wb[j];
#pragma unroll
        for (int off = 16; off > 0; off >>= 1) {
            a += __shfl_xor(a, off, 32);
            b += __shfl_xor(b, off, 32);
        }
        if (j == 0) ((float2*)outw)[n] = make_float2(a * dv, b * dv);
    }
}

// ---------- head aggregation -> outputs ----------
__global__ __launch_bounds__(256) void k_gscal(const unsigned* __restrict__ edat,
                                               const unsigned* __restrict__ rowptr,
                                               const float* __restrict__ dinv,
                                               const float2* __restrict__ head_w,
                                               const float* __restrict__ b2,
                                               const float* __restrict__ bs,
                                               float* __restrict__ out) {
    int gid = blockIdx.x * 256 + threadIdx.x;        // exact NN*32/256
    int n = gid >> 5, l = gid & 31;
    unsigned s0 = rowptr[n], s1 = rowptr[n + 1];
    float a = 0.f, b = 0.f;
    for (unsigned i = s0 + l; i < s1; i += 32) {
        float2 w = head_w[edat[i]];                  // 8B random, L2-resident table
        a += w.x; b += w.y;
    }
#pragma unroll
    for (int off = 16; off > 0; off >>= 1) {
        a += __shfl_xor(a, off, 32);
        b += __shfl_xor(b, off, 32);
    }
    if (l == 0) {
        float dv = dinv[n];
        float2 self = head_w[n];
        out[n]      = dv * (a + self.x) + b2[0];
        out[NN + n] = dv * (b + self.y) + bs[0];
    }
}

extern "C" void kernel_launch(void* const* d_in, const int* in_sizes, int n_in,
                              void* d_out, int out_size, void* d_ws, size_t ws_size,
                              hipStream_t stream) {
    const float* x   = (const float*)d_in[0];
    const int*   ei  = (const int*)d_in[1];
    const int*   src = ei;
    const int*   dst = ei + NE;
    const float* W1  = (const float*)d_in[2];
    const float* b1  = (const float*)d_in[3];
    const float* Wh  = (const float*)d_in[4];
    const float* bh  = (const float*)d_in[5];
    const float* W2  = (const float*)d_in[6];
    const float* b2  = (const float*)d_in[7];
    const float* Wsp = (const float*)d_in[8];
    const float* bs  = (const float*)d_in[9];
    float* out = (float*)d_out;

    // workspace (4B words), ~37 MB:
    // edat[1.6M] | hw1[3.2M] | @4.8M: rank[1.6M] + base[0.8M] (both dead before hw2) / hw2[3.2M]
    // | rowptr[100004] | cnt[8*NN] | dinv[NN] | headw[2*NN] | bsum[128]
    unsigned* w      = (unsigned*)d_ws;
    unsigned* edat   = w;
    float*    hw1    = (float*)(w + 1600000);
    unsigned* rank   = w + 4800000;                  // aliases hw2[0 .. 1.6M)
    unsigned* base   = w + 6400000;                  // aliases hw2[1.6M .. 2.4M)
    float*    hw2    = (float*)(w + 4800000);
    unsigned* rowptr = w + 8000000;
    unsigned* cnt    = rowptr + 100004;              // 16B-aligned (100004 % 4 == 0)
    float*    dinv   = (float*)(cnt + NC * NN);
    float*    headw  = dinv + NN;                    // float2[NN]
    unsigned* bsum   = (unsigned*)(headw + 2 * NN);

    // CSR build (XCD-privatized histogram; no-atomic fill)
    hipMemsetAsync(cnt, 0, NC * NN * sizeof(unsigned), stream);
    k_count<<<NE / 256, 256, 0, stream>>>(dst, cnt, rank);
    k_scanA<<<NSB, 256, 0, stream>>>((const uint4*)cnt, bsum);
    k_scanB<<<1, 128, 0, stream>>>(bsum, rowptr);
    k_scanC<<<NSB, 256, 0, stream>>>((const uint4*)cnt, bsum, (uint4*)rowptr,
                                     (float4*)dinv, (uint4*)base);
    k_fill<<<NE / 256, 256, 0, stream>>>(src, dst, rank, base, edat);

    // conv1 transform (pre-scaled by dinv)
    k_mm128<<<(NN + 255) / 256, 256, 0, stream>>>(x, W1, dinv, hw1);
    // conv1 aggregate + fused conv2 transform
    k_gather<1><<<NN * HD / 256, 256, 0, stream>>>(edat, rowptr, dinv, hw1, b1, Wh, nullptr, hw2);
    // conv2 aggregate + fused heads
    k_gather<2><<<NN * HD / 256, 256, 0, stream>>>(edat, rowptr, dinv, hw2, bh, W2, Wsp, headw);
    // head aggregation -> outputs
    k_gscal<<<NN * HD / 256, 256, 0, stream>>>(edat, rowptr, dinv, (const float2*)headw, b2, bs, out);
}

// Round 8
// 286.444 us; speedup vs baseline: 1.1645x; 1.1645x over previous
//
#include <hip/hip_runtime.h>

#define NN 100000
#define NE 1600000
#define SD 128
#define HD 32
#define NBK 391        // buckets of 256 nodes: ceil(100000/256)
#define EPB 4000       // edges per block in P1/P3
#define NBLK 400       // NBLK*EPB == NE exactly
#define MAXBE 6144     // max edges per bucket (mean 4096, sd 64 -> +32 sigma)

// ---------- P1: per-block bucket histogram + global reservation ----------
__global__ __launch_bounds__(256) void k_p1(const int* __restrict__ dst,
                                            unsigned* __restrict__ bktcnt,
                                            unsigned* __restrict__ blockbase) {
    __shared__ unsigned h[NBK];
    int blk = blockIdx.x, tid = threadIdx.x;
    for (int i = tid; i < NBK; i += 256) h[i] = 0;
    __syncthreads();
    int e0 = blk * EPB;
    for (int i = tid; i < EPB; i += 256)
        atomicAdd(&h[(unsigned)dst[e0 + i] >> 8], 1u);
    __syncthreads();
    for (int i = tid; i < NBK; i += 256)
        blockbase[blk * NBK + i] = atomicAdd(&bktcnt[i], h[i]);   // 156K atomics total
}

// ---------- P2: scan bucket totals -> bucket bases ----------
__global__ __launch_bounds__(512) void k_p2(const unsigned* __restrict__ bktcnt,
                                            unsigned* __restrict__ bktbase,
                                            unsigned* __restrict__ rowptr) {
    __shared__ unsigned sc[512];
    int tid = threadIdx.x;
    unsigned c = (tid < NBK) ? bktcnt[tid] : 0u;
    sc[tid] = c;
    __syncthreads();
    for (int off = 1; off < 512; off <<= 1) {
        unsigned t = (tid >= off) ? sc[tid - off] : 0u;
        __syncthreads();
        sc[tid] += t;
        __syncthreads();
    }
    if (tid <= NBK) bktbase[tid] = sc[tid] - c;    // exclusive; bktbase[NBK] == NE
    if (tid == 0) rowptr[NN] = NE;
}

// ---------- P3: scatter edges into buckets (block-contiguous chunks) ----------
__global__ __launch_bounds__(256) void k_p3(const int* __restrict__ src,
                                            const int* __restrict__ dst,
                                            const unsigned* __restrict__ bktbase,
                                            const unsigned* __restrict__ blockbase,
                                            unsigned* __restrict__ ebuf) {
    __shared__ unsigned cur[NBK];
    int blk = blockIdx.x, tid = threadIdx.x;
    for (int i = tid; i < NBK; i += 256)
        cur[i] = bktbase[i] + blockbase[blk * NBK + i];
    __syncthreads();
    int e0 = blk * EPB;
    for (int i = tid; i < EPB; i += 256) {
        int d = dst[e0 + i];
        unsigned s = (unsigned)src[e0 + i];
        unsigned b = (unsigned)d >> 8;
        unsigned pos = atomicAdd(&cur[b], 1u);     // LDS atomic
        ebuf[pos] = ((unsigned)(d & 255) << 20) | s;   // pack d_local | src (<2^17)
    }
}

// ---------- P4: per-bucket CSR finalize (in-place), rowptr + dinv ----------
__global__ __launch_bounds__(256) void k_p4(unsigned* __restrict__ ebuf,
                                            const unsigned* __restrict__ bktbase,
                                            unsigned* __restrict__ rowptr,
                                            float* __restrict__ dinv) {
    __shared__ unsigned eL[MAXBE];
    __shared__ unsigned hist[256];
    __shared__ unsigned sc[256];
    int b = blockIdx.x, tid = threadIdx.x;
    unsigned base = bktbase[b], nE = bktbase[b + 1] - base;
    int n0 = b << 8;
    int nodes = min(256, NN - n0);
    for (unsigned i = tid; i < nE; i += 256) eL[i] = ebuf[base + i];
    hist[tid] = 0;
    __syncthreads();
    for (unsigned i = tid; i < nE; i += 256) atomicAdd(&hist[eL[i] >> 20], 1u);
    __syncthreads();
    unsigned c = hist[tid];
    sc[tid] = c;
    __syncthreads();
    for (int off = 1; off < 256; off <<= 1) {
        unsigned t = (tid >= off) ? sc[tid - off] : 0u;
        __syncthreads();
        sc[tid] += t;
        __syncthreads();
    }
    unsigned excl = sc[tid] - c;
    if (tid < nodes) {
        rowptr[n0 + tid] = base + excl;
        dinv[n0 + tid] = rsqrtf((float)c + 1.0f);
    }
    hist[tid] = base + excl;                       // reuse as cursor
    __syncthreads();
    for (unsigned i = tid; i < nE; i += 256) {
        unsigned v = eL[i];
        unsigned pos = atomicAdd(&hist[v >> 20], 1u);
        ebuf[pos] = v & 0xFFFFFu;                  // in-place: all reads done from LDS
    }
}

// ---------- hw = (X @ W1) * dinv[n] : 256 nodes/block, thread = 8n x 4f ----------
__global__ __launch_bounds__(256) void k_mm128(const float* __restrict__ X,
                                               const float* __restrict__ W,
                                               const float* __restrict__ dinv,
                                               float* __restrict__ out) {
    __shared__ float Wls[SD * HD];       // 16 KB
    __shared__ float xT[32][260];        // 33.3 KB
    int tid = threadIdx.x;
    {
        const float4* W4 = (const float4*)W;
        float4* Wl4 = (float4*)Wls;
        for (int i = tid; i < SD * HD / 4; i += 256) Wl4[i] = W4[i];
    }
    int nb = blockIdx.x * 256;
    int g = tid & 7;
    int q = tid >> 3;
    float acc[8][4] = {};
    for (int kc = 0; kc < SD; kc += 32) {
        __syncthreads();
        for (int i = tid; i < 256 * 8; i += 256) {
            int n = i >> 3, k4 = i & 7;
            int node = nb + n;
            float4 v = (node < NN) ? *(const float4*)&X[(size_t)node * SD + kc + k4 * 4]
                                   : make_float4(0.f, 0.f, 0.f, 0.f);
            xT[k4 * 4 + 0][n] = v.x;
            xT[k4 * 4 + 1][n] = v.y;
            xT[k4 * 4 + 2][n] = v.z;
            xT[k4 * 4 + 3][n] = v.w;
        }
        __syncthreads();
#pragma unroll
        for (int kk = 0; kk < 32; ++kk) {
            const float4 xa = *(const float4*)&xT[kk][q * 8];
            const float4 xb = *(const float4*)&xT[kk][q * 8 + 4];
            const float4 wv = *(const float4*)&Wls[(kc + kk) * HD + g * 4];
            acc[0][0] = fmaf(xa.x, wv.x, acc[0][0]);
            acc[0][1] = fmaf(xa.x, wv.y, acc[0][1]);
            acc[0][2] = fmaf(xa.x, wv.z, acc[0][2]);
            acc[0][3] = fmaf(xa.x, wv.w, acc[0][3]);
            acc[1][0] = fmaf(xa.y, wv.x, acc[1][0]);
            acc[1][1] = fmaf(xa.y, wv.y, acc[1][1]);
            acc[1][2] = fmaf(xa.y, wv.z, acc[1][2]);
            acc[1][3] = fmaf(xa.y, wv.w, acc[1][3]);
            acc[2][0] = fmaf(xa.z, wv.x, acc[2][0]);
            acc[2][1] = fmaf(xa.z, wv.y, acc[2][1]);
            acc[2][2] = fmaf(xa.z, wv.z, acc[2][2]);
            acc[2][3] = fmaf(xa.z, wv.w, acc[2][3]);
            acc[3][0] = fmaf(xa.w, wv.x, acc[3][0]);
            acc[3][1] = fmaf(xa.w, wv.y, acc[3][1]);
            acc[3][2] = fmaf(xa.w, wv.z, acc[3][2]);
            acc[3][3] = fmaf(xa.w, wv.w, acc[3][3]);
            acc[4][0] = fmaf(xb.x, wv.x, acc[4][0]);
            acc[4][1] = fmaf(xb.x, wv.y, acc[4][1]);
            acc[4][2] = fmaf(xb.x, wv.z, acc[4][2]);
            acc[4][3] = fmaf(xb.x, wv.w, acc[4][3]);
            acc[5][0] = fmaf(xb.y, wv.x, acc[5][0]);
            acc[5][1] = fmaf(xb.y, wv.y, acc[5][1]);
            acc[5][2] = fmaf(xb.y, wv.z, acc[5][2]);
            acc[5][3] = fmaf(xb.y, wv.w, acc[5][3]);
            acc[6][0] = fmaf(xb.z, wv.x, acc[6][0]);
            acc[6][1] = fmaf(xb.z, wv.y, acc[6][1]);
            acc[6][2] = fmaf(xb.z, wv.z, acc[6][2]);
            acc[6][3] = fmaf(xb.z, wv.w, acc[6][3]);
            acc[7][0] = fmaf(xb.w, wv.x, acc[7][0]);
            acc[7][1] = fmaf(xb.w, wv.y, acc[7][1]);
            acc[7][2] = fmaf(xb.w, wv.z, acc[7][2]);
            acc[7][3] = fmaf(xb.w, wv.w, acc[7][3]);
        }
    }
#pragma unroll
    for (int r = 0; r < 8; ++r) {
        int node = nb + q * 8 + r;
        if (node < NN) {
            float dv = dinv[node];
            float4 o = {acc[r][0] * dv, acc[r][1] * dv, acc[r][2] * dv, acc[r][3] * dv};
            *(float4*)&out[(size_t)node * HD + g * 4] = o;
        }
    }
}

// ---------- gather aggregation; 32 lanes = 32 features per node ----------
template <int MODE>
__global__ __launch_bounds__(256) void k_gather(const unsigned* __restrict__ edat,
                                                const unsigned* __restrict__ rowptr,
                                                const float* __restrict__ dinv,
                                                const float* __restrict__ hw,
                                                const float* __restrict__ bias,
                                                const float* __restrict__ Wa,
                                                const float* __restrict__ Wb,
                                                float* __restrict__ outw) {
    int gid = blockIdx.x * 256 + threadIdx.x;        // exact NN*32/256
    int n = gid >> 5, j = gid & 31;
    unsigned s0 = rowptr[n], s1 = rowptr[n + 1];
    float acc = 0.f;
    unsigned i = s0;
    for (; i + 4 <= s1; i += 4) {
        unsigned e0 = edat[i], e1 = edat[i + 1], e2 = edat[i + 2], e3 = edat[i + 3];
        float v0 = hw[(size_t)e0 * HD + j];
        float v1 = hw[(size_t)e1 * HD + j];
        float v2 = hw[(size_t)e2 * HD + j];
        float v3 = hw[(size_t)e3 * HD + j];
        acc += (v0 + v1) + (v2 + v3);
    }
    for (; i < s1; ++i) acc += hw[(size_t)edat[i] * HD + j];
    float dv = dinv[n];
    float v = dv * (acc + hw[(size_t)n * HD + j]) + bias[j];
    if (MODE == 1) {
        float h2 = 0.f;
#pragma unroll
        for (int jj = 0; jj < 32; ++jj)
            h2 = fmaf(__shfl(v, jj, 32), Wa[jj * HD + j], h2);
        outw[(size_t)n * HD + j] = h2 * dv;
    } else {
        float a = fmaxf(v, 0.f) * Wa[j];
        float b = v * Wb[j];
#pragma unroll
        for (int off = 16; off > 0; off >>= 1) {
            a += __shfl_xor(a, off, 32);
            b += __shfl_xor(b, off, 32);
        }
        if (j == 0) ((float2*)outw)[n] = make_float2(a * dv, b * dv);
    }
}

// ---------- head aggregation -> outputs ----------
__global__ __launch_bounds__(256) void k_gscal(const unsigned* __restrict__ edat,
                                               const unsigned* __restrict__ rowptr,
                                               const float* __restrict__ dinv,
                                               const float2* __restrict__ head_w,
                                               const float* __restrict__ b2,
                                               const float* __restrict__ bs,
                                               float* __restrict__ out) {
    int gid = blockIdx.x * 256 + threadIdx.x;        // exact NN*32/256
    int n = gid >> 5, l = gid & 31;
    unsigned s0 = rowptr[n], s1 = rowptr[n + 1];
    float a = 0.f, b = 0.f;
    for (unsigned i = s0 + l; i < s1; i += 32) {
        float2 w = head_w[edat[i]];
        a += w.x; b += w.y;
    }
#pragma unroll
    for (int off = 16; off > 0; off >>= 1) {
        a += __shfl_xor(a, off, 32);
        b += __shfl_xor(b, off, 32);
    }
    if (l == 0) {
        float dv = dinv[n];
        float2 self = head_w[n];
        out[n]      = dv * (a + self.x) + b2[0];
        out[NN + n] = dv * (b + self.y) + bs[0];
    }
}

extern "C" void kernel_launch(void* const* d_in, const int* in_sizes, int n_in,
                              void* d_out, int out_size, void* d_ws, size_t ws_size,
                              hipStream_t stream) {
    const float* x   = (const float*)d_in[0];
    const int*   ei  = (const int*)d_in[1];
    const int*   src = ei;
    const int*   dst = ei + NE;
    const float* W1  = (const float*)d_in[2];
    const float* b1  = (const float*)d_in[3];
    const float* Wh  = (const float*)d_in[4];
    const float* bh  = (const float*)d_in[5];
    const float* W2  = (const float*)d_in[6];
    const float* b2  = (const float*)d_in[7];
    const float* Wsp = (const float*)d_in[8];
    const float* bs  = (const float*)d_in[9];
    float* out = (float*)d_out;

    // workspace (u32 words), total ~34.2 MB:
    // edat/bucketed 0..1.6M | blockbase 1.6M..1.7564M | hw1 @1.76M [3.2M] |
    // hw2 @4.96M [3.2M] | rowptr @8.16M [100004] | bktcnt @8.260004M [396] |
    // bktbase @8.2604M [400] | dinv @8.2608M [100K] | headw @8.3608M [200K]
    unsigned* w         = (unsigned*)d_ws;
    unsigned* edat      = w;                          // bucketed, then CSR in-place
    unsigned* blockbase = w + 1600000;
    float*    hw1       = (float*)(w + 1760000);
    float*    hw2       = (float*)(w + 4960000);
    unsigned* rowptr    = w + 8160000;
    unsigned* bktcnt    = w + 8260004;
    unsigned* bktbase   = w + 8260400;
    float*    dinv      = (float*)(w + 8260800);
    float*    headw     = (float*)(w + 8360800);      // float2[NN]

    // CSR build: bucketed counting sort, no global data atomics
    hipMemsetAsync(bktcnt, 0, NBK * sizeof(unsigned), stream);
    k_p1<<<NBLK, 256, 0, stream>>>(dst, bktcnt, blockbase);
    k_p2<<<1, 512, 0, stream>>>(bktcnt, bktbase, rowptr);
    k_p3<<<NBLK, 256, 0, stream>>>(src, dst, bktbase, blockbase, edat);
    k_p4<<<NBK, 256, 0, stream>>>(edat, bktbase, rowptr, dinv);

    // conv1 transform (pre-scaled by dinv)
    k_mm128<<<(NN + 255) / 256, 256, 0, stream>>>(x, W1, dinv, hw1);
    // conv1 aggregate + fused conv2 transform
    k_gather<1><<<NN * HD / 256, 256, 0, stream>>>(edat, rowptr, dinv, hw1, b1, Wh, nullptr, hw2);
    // conv2 aggregate + fused heads
    k_gather<2><<<NN * HD / 256, 256, 0, stream>>>(edat, rowptr, dinv, hw2, bh, W2, Wsp, headw);
    // head aggregation -> outputs
    k_gscal<<<NN * HD / 256, 256, 0, stream>>>(edat, rowptr, dinv, (const float2*)headw, b2, bs, out);
}